// Round 2
// baseline (611.513 us; speedup 1.0000x reference)
//
#include <hip/hip_runtime.h>
#include <float.h>
#include <math.h>

#define TOKS 16384
#define HDIM 4096
#define NEXP 64
#define TB   64                 // tokens per block
#define HC   16                 // h per chunk
#define NWAVE 8
#define HSLICE (HDIM / NWAVE)   // 512 h per wave
#define NCH (HSLICE / HC)       // 32 chunks

// Block: 512 thr = 8 waves. Block tile 64 tok x 64 exp; wave wv owns h in
// [wv*512, wv*512+512). Lane (tx=lane&7, ey=lane>>3) owns an 8 tok x 8 exp
// register tile (64 acc). Per h: 4 ds_read_b128 -> 64 FMAs.
// Per-wave PRIVATE double-buffered LDS staging -> zero barriers in main loop.
// LDS: 8 waves * 2 buf * (xs[16][64] + ws[16][64]) = 128 KiB; reduction aliases.
__global__ __launch_bounds__(512, 2)
void topk_router_kernel(const float* __restrict__ x,
                        const float* __restrict__ wgt,
                        const float* __restrict__ bias,
                        float* __restrict__ out)
{
  __shared__ __align__(16) float smem[32768];   // 128 KiB
  const int tid  = threadIdx.x;
  const int lane = tid & 63;
  const int wv   = tid >> 6;
  const int tokBase = blockIdx.x * TB;

  float* const slab = smem + wv * 4096;   // 16 KiB per wave
  float* const xs0 = slab;                // [16][64]
  float* const ws0 = slab + 1024;
  float* const xs1 = slab + 2048;
  float* const ws1 = slab + 3072;

  const int tx = lane & 7;          // token-group in compute
  const int ey = lane >> 3;         // expert-group in compute
  const int sa = lane & 31;         // staging: rows 2sa, 2sa+1
  const int sh = (lane >> 5) * 8;   // staging: h-offset 0 or 8

  const int hbase = wv * HSLICE;
  const float* const xg = x   + (size_t)(tokBase + 2 * sa) * HDIM + hbase + sh;
  const float* const wg = wgt + (size_t)(2 * sa) * HDIM + hbase + sh;

  float acc[64];
#pragma unroll
  for (int i = 0; i < 64; ++i) acc[i] = 0.f;

  float4 rxa, rxb, rxc, rxd, rwa, rwb, rwc, rwd;

  // issue 8 global b128 loads for chunk c into regs (2 rows x 32B, per matrix)
#define LOADC(c) do { \
    const float* p_ = xg + (c) * HC; \
    rxa = *(const float4*)(p_);           rxb = *(const float4*)(p_ + 4); \
    rxc = *(const float4*)(p_ + HDIM);    rxd = *(const float4*)(p_ + HDIM + 4); \
    const float* q_ = wg + (c) * HC; \
    rwa = *(const float4*)(q_);           rwb = *(const float4*)(q_ + 4); \
    rwc = *(const float4*)(q_ + HDIM);    rwd = *(const float4*)(q_ + HDIM + 4); \
  } while (0)

#define ST2(dst, a, b) *(float2*)(dst) = make_float2((a), (b))

  // transpose-write staged regs into LDS [h][row]: 16 ds_write_b64, 2-way banks
#define WRITEC(xs, ws) do { \
    float* xr_ = (xs) + sh * 64 + 2 * sa; \
    ST2(xr_ + 0 * 64, rxa.x, rxc.x); ST2(xr_ + 1 * 64, rxa.y, rxc.y); \
    ST2(xr_ + 2 * 64, rxa.z, rxc.z); ST2(xr_ + 3 * 64, rxa.w, rxc.w); \
    ST2(xr_ + 4 * 64, rxb.x, rxd.x); ST2(xr_ + 5 * 64, rxb.y, rxd.y); \
    ST2(xr_ + 6 * 64, rxb.z, rxd.z); ST2(xr_ + 7 * 64, rxb.w, rxd.w); \
    float* wr_ = (ws) + sh * 64 + 2 * sa; \
    ST2(wr_ + 0 * 64, rwa.x, rwc.x); ST2(wr_ + 1 * 64, rwa.y, rwc.y); \
    ST2(wr_ + 2 * 64, rwa.z, rwc.z); ST2(wr_ + 3 * 64, rwa.w, rwc.w); \
    ST2(wr_ + 4 * 64, rwb.x, rwd.x); ST2(wr_ + 5 * 64, rwb.y, rwd.y); \
    ST2(wr_ + 6 * 64, rwb.z, rwd.z); ST2(wr_ + 7 * 64, rwb.w, rwd.w); \
  } while (0)

  // 16 h-steps: per h 4 ds_read_b128 (broadcast/2-way) + 64 fmaf
#define FMAC(xs, ws) do { \
    _Pragma("unroll") \
    for (int h = 0; h < HC; ++h) { \
      const float4 xa_ = *(const float4*)((xs) + h * 64 + tx * 8); \
      const float4 xb_ = *(const float4*)((xs) + h * 64 + tx * 8 + 4); \
      const float4 wa_ = *(const float4*)((ws) + h * 64 + ey * 8); \
      const float4 wb_ = *(const float4*)((ws) + h * 64 + ey * 8 + 4); \
      const float xv_[8]  = {xa_.x, xa_.y, xa_.z, xa_.w, xb_.x, xb_.y, xb_.z, xb_.w}; \
      const float wvv_[8] = {wa_.x, wa_.y, wa_.z, wa_.w, wb_.x, wb_.y, wb_.z, wb_.w}; \
      _Pragma("unroll") \
      for (int i_ = 0; i_ < 8; ++i_) { \
        _Pragma("unroll") \
        for (int j_ = 0; j_ < 8; ++j_) \
          acc[i_ * 8 + j_] = fmaf(xv_[i_], wvv_[j_], acc[i_ * 8 + j_]); \
      } \
    } \
  } while (0)

  // ---- software-pipelined main loop: no __syncthreads(), wave-private bufs ----
  LOADC(0);
  WRITEC(xs0, ws0);
  LOADC(1);
  for (int c = 0; c < NCH; c += 2) {
    WRITEC(xs1, ws1);                    // chunk c+1 regs -> LDS
    if (c + 2 < NCH) LOADC(c + 2);       // prefetch chunk c+2
    FMAC(xs0, ws0);                      // compute chunk c
    if (c + 2 < NCH) WRITEC(xs0, ws0);   // chunk c+2 regs -> LDS
    if (c + 3 < NCH) LOADC(c + 3);       // prefetch chunk c+3
    FMAC(xs1, ws1);                      // compute chunk c+1
  }

  // ---- cross-wave reduction: red[p][64 tok][64 e], p=0..3 aliases slabs 0..3 ----
#define TILE_W(plane) do { \
    float* rp_ = smem + (plane) * 4096 + ey * 8; \
    _Pragma("unroll") \
    for (int i_ = 0; i_ < 8; ++i_) { \
      float* q_ = rp_ + (tx * 8 + i_) * 64; \
      *(float4*)(q_)     = make_float4(acc[i_*8+0], acc[i_*8+1], acc[i_*8+2], acc[i_*8+3]); \
      *(float4*)(q_ + 4) = make_float4(acc[i_*8+4], acc[i_*8+5], acc[i_*8+6], acc[i_*8+7]); \
    } \
  } while (0)

  __syncthreads();                       // all waves done reading their slabs
  if (wv >= 4) TILE_W(wv - 4);           // waves 4..7 write partial plane
  __syncthreads();
  if (wv < 4) {                          // waves 0..3: acc += plane, write back
    const float* rp = smem + wv * 4096 + ey * 8;
#pragma unroll
    for (int i = 0; i < 8; ++i) {
      const float4 a = *(const float4*)(rp + (tx * 8 + i) * 64);
      const float4 b = *(const float4*)(rp + (tx * 8 + i) * 64 + 4);
      acc[i*8+0] += a.x; acc[i*8+1] += a.y; acc[i*8+2] += a.z; acc[i*8+3] += a.w;
      acc[i*8+4] += b.x; acc[i*8+5] += b.y; acc[i*8+6] += b.z; acc[i*8+7] += b.w;
    }
    TILE_W(wv);
  }
  __syncthreads();
  // ---- final 4-plane sum + bias -> fin[64][64] at smem+16384 (slab 4, free) ----
  {
    const int t  = tid >> 3;
    const int e0 = (tid & 7) * 8;
    float4 s0 = *(const float4*)&bias[e0];
    float4 s1 = *(const float4*)&bias[e0 + 4];
#pragma unroll
    for (int p = 0; p < 4; ++p) {
      const float4 a = *(const float4*)&smem[p * 4096 + t * 64 + e0];
      const float4 b = *(const float4*)&smem[p * 4096 + t * 64 + e0 + 4];
      s0.x += a.x; s0.y += a.y; s0.z += a.z; s0.w += a.w;
      s1.x += b.x; s1.y += b.y; s1.z += b.z; s1.w += b.w;
    }
    *(float4*)&smem[16384 + t * 64 + e0]     = s0;
    *(float4*)&smem[16384 + t * 64 + e0 + 4] = s1;
  }
  __syncthreads();

  // ---- top-8 + softmax: wave wv handles tokens wv*8 .. wv*8+7 ----
  const float* fin = smem + 16384;
  for (int tt = 0; tt < 8; ++tt) {
    const int t = wv * 8 + tt;
    float v = fin[t * 64 + lane];        // lane = expert id
    float myval = 0.f, m0 = 0.f;
    int myidx = 0;
#pragma unroll
    for (int k = 0; k < 8; ++k) {
      float bv = v;
      int   bi = lane;
#pragma unroll
      for (int off = 1; off < 64; off <<= 1) {   // argmax, min-index tiebreak
        const float ov = __shfl_xor(bv, off);
        const int   oi = __shfl_xor(bi, off);
        if (ov > bv || (ov == bv && oi < bi)) { bv = ov; bi = oi; }
      }
      if (k == 0) m0 = bv;
      if (lane == k) { myval = bv; myidx = bi; }
      if (lane == bi) v = -FLT_MAX;      // bi is wave-uniform
    }
    const float el = (lane < 8) ? expf(myval - m0) : 0.f;
    float ssum = el;
    ssum += __shfl_xor(ssum, 1);
    ssum += __shfl_xor(ssum, 2);
    ssum += __shfl_xor(ssum, 4);
    if (lane < 8) {
      const size_t tg = (size_t)(tokBase + t);
      out[tg * 8 + lane] = el / ssum;                        // weights (f32)
      out[(size_t)TOKS * 8 + tg * 8 + lane] = (float)myidx;  // indices as f32
    }
  }
}

extern "C" void kernel_launch(void* const* d_in, const int* in_sizes, int n_in,
                              void* d_out, int out_size, void* d_ws, size_t ws_size,
                              hipStream_t stream) {
  const float* x    = (const float*)d_in[0];
  const float* wgt  = (const float*)d_in[1];
  const float* bias = (const float*)d_in[2];
  float* out = (float*)d_out;
  hipLaunchKernelGGL(topk_router_kernel, dim3(TOKS / TB), dim3(512), 0, stream,
                     x, wgt, bias, out);
}

// Round 3
// 608.462 us; speedup vs baseline: 1.0050x; 1.0050x over previous
//
#include <hip/hip_runtime.h>
#include <float.h>
#include <math.h>

#define TOKS 16384
#define HDIM 4096
#define NEXP 64
#define TB   64                 // tokens per block
#define HC   16                 // h per chunk
#define NWAVE 8
#define HSLICE (HDIM / NWAVE)   // 512 h per wave
#define NCH (HSLICE / HC)       // 32 chunks

// Block: 512 thr = 8 waves. Block tile 64 tok x 64 exp; wave wv owns h in
// [wv*512, wv*512+512). Lane (tx=lane&7, ey=lane>>3) owns an 8 tok x 8 exp
// register tile (64 acc VGPRs, all indices compile-time const -> no scratch).
// Per h: 4 ds_read_b128 (broadcast-heavy, ~2-4cyc each) -> 64 FMAs.
// Per-wave PRIVATE double-buffered LDS staging -> zero barriers in main loop.
__global__ __launch_bounds__(512, 2)
void topk_router_kernel(const float* __restrict__ x,
                        const float* __restrict__ wgt,
                        const float* __restrict__ bias,
                        float* __restrict__ out)
{
  __shared__ __align__(16) float smem[32768];   // 128 KiB
  const int tid  = threadIdx.x;
  const int lane = tid & 63;
  const int wv   = tid >> 6;
  const int tokBase = blockIdx.x * TB;

  float* const slab = smem + wv * 4096;   // 16 KiB per wave
  float* const xs0 = slab;                // [16 h][64 tok]
  float* const ws0 = slab + 1024;         // [16 h][64 exp]
  float* const xs1 = slab + 2048;
  float* const ws1 = slab + 3072;

  const int tx = lane & 7;          // token-group in compute
  const int ey = lane >> 3;         // expert-group in compute
  const int sa = lane & 31;         // staging: rows 2sa, 2sa+1
  const int sh = (lane >> 5) * 8;   // staging: h-offset 0 or 8

  const int hbase = wv * HSLICE;
  const float* const xg = x   + (size_t)(tokBase + 2 * sa) * HDIM + hbase + sh;
  const float* const wg = wgt + (size_t)(2 * sa) * HDIM + hbase + sh;

  float acc[64];
#pragma unroll
  for (int i = 0; i < 64; ++i) acc[i] = 0.f;

  float4 rxa, rxb, rxc, rxd, rwa, rwb, rwc, rwd;

#define LOADC(c) do { \
    const float* p_ = xg + (c) * HC; \
    rxa = *(const float4*)(p_);           rxb = *(const float4*)(p_ + 4); \
    rxc = *(const float4*)(p_ + HDIM);    rxd = *(const float4*)(p_ + HDIM + 4); \
    const float* q_ = wg + (c) * HC; \
    rwa = *(const float4*)(q_);           rwb = *(const float4*)(q_ + 4); \
    rwc = *(const float4*)(q_ + HDIM);    rwd = *(const float4*)(q_ + HDIM + 4); \
  } while (0)

#define ST2(dst, a, b) *(float2*)(dst) = make_float2((a), (b))

  // transpose-write staged regs into LDS [h][row]: 16 ds_write_b64, 2-way banks
#define WRITEC(xs, ws) do { \
    float* xr_ = (xs) + sh * 64 + 2 * sa; \
    ST2(xr_ + 0 * 64, rxa.x, rxc.x); ST2(xr_ + 1 * 64, rxa.y, rxc.y); \
    ST2(xr_ + 2 * 64, rxa.z, rxc.z); ST2(xr_ + 3 * 64, rxa.w, rxc.w); \
    ST2(xr_ + 4 * 64, rxb.x, rxd.x); ST2(xr_ + 5 * 64, rxb.y, rxd.y); \
    ST2(xr_ + 6 * 64, rxb.z, rxd.z); ST2(xr_ + 7 * 64, rxb.w, rxd.w); \
    float* wr_ = (ws) + sh * 64 + 2 * sa; \
    ST2(wr_ + 0 * 64, rwa.x, rwc.x); ST2(wr_ + 1 * 64, rwa.y, rwc.y); \
    ST2(wr_ + 2 * 64, rwa.z, rwc.z); ST2(wr_ + 3 * 64, rwa.w, rwc.w); \
    ST2(wr_ + 4 * 64, rwb.x, rwd.x); ST2(wr_ + 5 * 64, rwb.y, rwd.y); \
    ST2(wr_ + 6 * 64, rwb.z, rwd.z); ST2(wr_ + 7 * 64, rwb.w, rwd.w); \
  } while (0)

  // 8 FMAs against one broadcast x value; all acc indices compile-time const
#define FMA8(b, xval) \
    acc[(b)+0] = fmaf((xval), wa_.x, acc[(b)+0]); \
    acc[(b)+1] = fmaf((xval), wa_.y, acc[(b)+1]); \
    acc[(b)+2] = fmaf((xval), wa_.z, acc[(b)+2]); \
    acc[(b)+3] = fmaf((xval), wa_.w, acc[(b)+3]); \
    acc[(b)+4] = fmaf((xval), wb_.x, acc[(b)+4]); \
    acc[(b)+5] = fmaf((xval), wb_.y, acc[(b)+5]); \
    acc[(b)+6] = fmaf((xval), wb_.z, acc[(b)+6]); \
    acc[(b)+7] = fmaf((xval), wb_.w, acc[(b)+7]);

  // 16 h-steps: per h 4 ds_read_b128 (broadcast/2-way) + 64 fmaf, zero arrays
#define FMAC(xs, ws) do { \
    _Pragma("unroll") \
    for (int h = 0; h < HC; ++h) { \
      const float4 xa_ = *(const float4*)((xs) + h * 64 + tx * 8); \
      const float4 xb_ = *(const float4*)((xs) + h * 64 + tx * 8 + 4); \
      const float4 wa_ = *(const float4*)((ws) + h * 64 + ey * 8); \
      const float4 wb_ = *(const float4*)((ws) + h * 64 + ey * 8 + 4); \
      FMA8(0,  xa_.x) FMA8(8,  xa_.y) FMA8(16, xa_.z) FMA8(24, xa_.w) \
      FMA8(32, xb_.x) FMA8(40, xb_.y) FMA8(48, xb_.z) FMA8(56, xb_.w) \
    } \
  } while (0)

  // ---- software-pipelined main loop: no __syncthreads(), wave-private bufs ----
  LOADC(0);
  WRITEC(xs0, ws0);
  LOADC(1);
  for (int c = 0; c < NCH; c += 2) {
    WRITEC(xs1, ws1);                    // chunk c+1 regs -> LDS
    if (c + 2 < NCH) LOADC(c + 2);       // prefetch chunk c+2
    FMAC(xs0, ws0);                      // compute chunk c
    if (c + 2 < NCH) WRITEC(xs0, ws0);   // chunk c+2 regs -> LDS
    if (c + 3 < NCH) LOADC(c + 3);       // prefetch chunk c+3
    FMAC(xs1, ws1);                      // compute chunk c+1
  }

  // ---- cross-wave reduction: red[p][64 tok][64 e], p=0..3 aliases slabs ----
#define TILE_W(plane) do { \
    float* rp_ = smem + (plane) * 4096 + ey * 8; \
    _Pragma("unroll") \
    for (int i_ = 0; i_ < 8; ++i_) { \
      float* q_ = rp_ + (tx * 8 + i_) * 64; \
      *(float4*)(q_)     = make_float4(acc[i_*8+0], acc[i_*8+1], acc[i_*8+2], acc[i_*8+3]); \
      *(float4*)(q_ + 4) = make_float4(acc[i_*8+4], acc[i_*8+5], acc[i_*8+6], acc[i_*8+7]); \
    } \
  } while (0)

  __syncthreads();                       // all waves done reading their slabs
  if (wv >= 4) TILE_W(wv - 4);           // waves 4..7 write partial plane
  __syncthreads();
  if (wv < 4) {                          // waves 0..3: acc += plane, write back
    const float* rp = smem + wv * 4096 + ey * 8;
#pragma unroll
    for (int i = 0; i < 8; ++i) {
      const float4 a = *(const float4*)(rp + (tx * 8 + i) * 64);
      const float4 b = *(const float4*)(rp + (tx * 8 + i) * 64 + 4);
      acc[i*8+0] += a.x; acc[i*8+1] += a.y; acc[i*8+2] += a.z; acc[i*8+3] += a.w;
      acc[i*8+4] += b.x; acc[i*8+5] += b.y; acc[i*8+6] += b.z; acc[i*8+7] += b.w;
    }
    TILE_W(wv);
  }
  __syncthreads();
  // ---- final 4-plane sum + bias -> fin[64][64] at smem+16384 (slab 4, free) ----
  {
    const int t  = tid >> 3;
    const int e0 = (tid & 7) * 8;
    float4 s0 = *(const float4*)&bias[e0];
    float4 s1 = *(const float4*)&bias[e0 + 4];
#pragma unroll
    for (int p = 0; p < 4; ++p) {
      const float4 a = *(const float4*)&smem[p * 4096 + t * 64 + e0];
      const float4 b = *(const float4*)&smem[p * 4096 + t * 64 + e0 + 4];
      s0.x += a.x; s0.y += a.y; s0.z += a.z; s0.w += a.w;
      s1.x += b.x; s1.y += b.y; s1.z += b.z; s1.w += b.w;
    }
    *(float4*)&smem[16384 + t * 64 + e0]     = s0;
    *(float4*)&smem[16384 + t * 64 + e0 + 4] = s1;
  }
  __syncthreads();

  // ---- top-8 + softmax: wave wv handles tokens wv*8 .. wv*8+7 ----
  const float* fin = smem + 16384;
  for (int tt = 0; tt < 8; ++tt) {
    const int t = wv * 8 + tt;
    float v = fin[t * 64 + lane];        // lane = expert id
    float myval = 0.f, m0 = 0.f;
    int myidx = 0;
#pragma unroll
    for (int k = 0; k < 8; ++k) {
      float bv = v;
      int   bi = lane;
#pragma unroll
      for (int off = 1; off < 64; off <<= 1) {   // argmax, min-index tiebreak
        const float ov = __shfl_xor(bv, off);
        const int   oi = __shfl_xor(bi, off);
        if (ov > bv || (ov == bv && oi < bi)) { bv = ov; bi = oi; }
      }
      if (k == 0) m0 = bv;
      if (lane == k) { myval = bv; myidx = bi; }
      if (lane == bi) v = -FLT_MAX;      // bi is wave-uniform
    }
    const float el = (lane < 8) ? expf(myval - m0) : 0.f;
    float ssum = el;
    ssum += __shfl_xor(ssum, 1);
    ssum += __shfl_xor(ssum, 2);
    ssum += __shfl_xor(ssum, 4);
    if (lane < 8) {
      const size_t tg = (size_t)(tokBase + t);
      out[tg * 8 + lane] = el / ssum;                        // weights (f32)
      out[(size_t)TOKS * 8 + tg * 8 + lane] = (float)myidx;  // indices as f32
    }
  }
}

extern "C" void kernel_launch(void* const* d_in, const int* in_sizes, int n_in,
                              void* d_out, int out_size, void* d_ws, size_t ws_size,
                              hipStream_t stream) {
  const float* x    = (const float*)d_in[0];
  const float* wgt  = (const float*)d_in[1];
  const float* bias = (const float*)d_in[2];
  float* out = (float*)d_out;
  hipLaunchKernelGGL(topk_router_kernel, dim3(TOKS / TB), dim3(512), 0, stream,
                     x, wgt, bias, out);
}